// Round 8
// baseline (314.424 us; speedup 1.0000x reference)
//
#include <hip/hip_runtime.h>

// Problem constants (fixed by the reference)
#define M 3
#define B 32
#define S 256
#define D 768
#define H 1024
#define MD (M * D)          // 2304
#define NP (M * (M - 1))    // 6 ordered (i,j) pairs
#define SCALE 0.03608439182435161f  // 1/sqrt(768)
#define LN_EPS 1e-5f

// Workspace layout (float offsets).
#define OFF_WMU   0         // [M][D]
#define OFF_WLV   2304      // [M][D]
#define OFF_WPGQ  4608      // [M][D]
#define OFF_WPK   6912      // [NP][D]
#define OFF_CMU   11520     // [M]
#define OFF_CLV   11523     // [M]
#define OFF_CPGQ  11526     // [M]
#define OFF_CPK   11529     // [NP]
#define OFF_PQ    11536     // [NP][B] final pq gate (pq_base * g0)
#define OFF_Q     11776     // [M][B][D]
#define OFF_QBK   85504     // [NP][B]
#define OFF_QK    85760     // [NP][B][D] reduced qk (147456)
#define OFF_MLH   233216    // [NP][B][8(h)][2(m,l)] = 3072
#define OFF_KLP   236288    // [256] per-block KL partials
#define OFF_AGG   236544    // [M][B][D]
#define OFF_FUSED 457728    // [B][MD]
#define OFF_FSUM  531520    // [8(h)][NP][B][D] (h stride 147456) = 1179648
#define OFF_WKT   1711168   // [M][D][D] Wk transposed (1769472)
#define OFF_ARENA 3480640   // Q partials (24 x 73728) -> agg partials (48 x 73728) -> out partials (72 x 32768)
#define OFF_ARENA2 7019584  // qk partials (24 x 147456) | Wqc partials (slots 48..72 x 73728) -> E/G partials (slots 0..48)

__device__ __forceinline__ float wave_reduce(float v) {
    #pragma unroll
    for (int o = 32; o > 0; o >>= 1) v += __shfl_down(v, o, 64);
    return v;
}

__device__ __forceinline__ float sigmoidf(float x) {
    return 1.0f / (1.0f + __expf(-x));
}

__device__ __forceinline__ float dot4(float4 a, float4 b) {
    return a.x * b.x + a.y * b.y + a.z * b.z + a.w * b.w;
}

__device__ __forceinline__ void fma4(float4& a, float s, float4 w) {
    a.x += s * w.x; a.y += s * w.y; a.z += s * w.z; a.w += s * w.w;
}

// 16-row GEMV core: xs[32][16] in LDS, thread owns float4 of e, acc[16].
#define GEMV16_BODY(WPTR, OUTBASE, ROWBASE_EXPR)                                   \
    {                                                                              \
        int e4 = threadIdx.x * 4;                                                  \
        const float* Wm = (WPTR);                                                  \
        float4 acc[16];                                                            \
        _Pragma("unroll")                                                          \
        for (int v = 0; v < 16; v++) acc[v] = make_float4(0.f, 0.f, 0.f, 0.f);     \
        for (int k = 0; k < 32; k++) {                                             \
            float4 w = *(const float4*)(Wm + k * D);                               \
            float4 x0 = *(const float4*)&xs[k][0];                                 \
            float4 x1 = *(const float4*)&xs[k][4];                                 \
            float4 x2 = *(const float4*)&xs[k][8];                                 \
            float4 x3 = *(const float4*)&xs[k][12];                                \
            fma4(acc[0], x0.x, w);  fma4(acc[1], x0.y, w);                         \
            fma4(acc[2], x0.z, w);  fma4(acc[3], x0.w, w);                         \
            fma4(acc[4], x1.x, w);  fma4(acc[5], x1.y, w);                         \
            fma4(acc[6], x1.z, w);  fma4(acc[7], x1.w, w);                         \
            fma4(acc[8], x2.x, w);  fma4(acc[9], x2.y, w);                         \
            fma4(acc[10], x2.z, w); fma4(acc[11], x2.w, w);                        \
            fma4(acc[12], x3.x, w); fma4(acc[13], x3.y, w);                        \
            fma4(acc[14], x3.z, w); fma4(acc[15], x3.w, w);                        \
        }                                                                          \
        _Pragma("unroll")                                                          \
        for (int v = 0; v < 16; v++)                                               \
            *(float4*)&ws[(OUTBASE) + (ROWBASE_EXPR + v) * 768 + e4] = acc[v];     \
    }

// L1: fused prep + Q partials (bb=16).
// blocks 0..71 vector-dots, 72..86 scalar consts, 87..518 Wk transpose,
// 519..662 Q GEMV partials (i 3, bg 2 (16 b), kc 24 (32 k)).
__global__ __launch_bounds__(256) void k_prep2(const float* feats,
        const float* Wq, const float* Wk,
        const float* bq, const float* bk,
        const float* mu_w, const float* mu_b, const float* lv_w, const float* lv_b,
        const float* pgq_w, const float* pgq_b, const float* pgk_w, const float* pgk_b,
        float* ws) {
    int blk = blockIdx.x;
    if (blk < 72) {
        int mat = blk / 12, rg = blk % 12;
        const float* Wm; const float *va, *vb, *vc;
        float *oa, *ob, *oc; int nv;
        if (mat < 3) {
            int i = mat;
            Wm = Wq + i * D * D;
            va = mu_w + i * D; vb = lv_w + i * D; vc = pgq_w + i * D;
            oa = ws + OFF_WMU + i * D; ob = ws + OFF_WLV + i * D; oc = ws + OFF_WPGQ + i * D;
            nv = 3;
        } else {
            int j = mat - 3;
            int i1 = (j == 0) ? 1 : 0, i2 = (j == 2) ? 1 : 2;
            int p1 = 2 * i1 + ((j < i1) ? j : j - 1);
            int p2 = 2 * i2 + ((j < i2) ? j : j - 1);
            Wm = Wk + j * D * D;
            va = pgk_w + i1 * D; vb = pgk_w + i2 * D; vc = va;
            oa = ws + OFF_WPK + p1 * D; ob = ws + OFF_WPK + p2 * D; oc = oa;
            nv = 2;
        }
        int wave = threadIdx.x >> 6, lane = threadIdx.x & 63;
        const float4* va4 = (const float4*)va;
        const float4* vb4 = (const float4*)vb;
        const float4* vc4 = (const float4*)vc;
        float4 A0 = va4[lane], A1 = va4[lane + 64], A2 = va4[lane + 128];
        float4 B0 = vb4[lane], B1 = vb4[lane + 64], B2 = vb4[lane + 128];
        float4 C0 = vc4[lane], C1 = vc4[lane + 64], C2 = vc4[lane + 128];
        int base = rg * 64 + wave * 16;
        for (int r = 0; r < 16; r += 2) {
            const float4* rowP = (const float4*)(Wm + (base + r) * D);
            const float4* rowQ = (const float4*)(Wm + (base + r + 1) * D);
            float4 x0 = rowP[lane], x1 = rowP[lane + 64], x2 = rowP[lane + 128];
            float4 y0 = rowQ[lane], y1 = rowQ[lane + 64], y2 = rowQ[lane + 128];
            float daP = dot4(x0, A0) + dot4(x1, A1) + dot4(x2, A2);
            float dbP = dot4(x0, B0) + dot4(x1, B1) + dot4(x2, B2);
            float dcP = dot4(x0, C0) + dot4(x1, C1) + dot4(x2, C2);
            float daQ = dot4(y0, A0) + dot4(y1, A1) + dot4(y2, A2);
            float dbQ = dot4(y0, B0) + dot4(y1, B1) + dot4(y2, B2);
            float dcQ = dot4(y0, C0) + dot4(y1, C1) + dot4(y2, C2);
            daP = wave_reduce(daP); dbP = wave_reduce(dbP);
            daQ = wave_reduce(daQ); dbQ = wave_reduce(dbQ);
            if (nv == 3) { dcP = wave_reduce(dcP); dcQ = wave_reduce(dcQ); }
            if (lane == 0) {
                oa[base + r] = daP; ob[base + r] = dbP;
                oa[base + r + 1] = daQ; ob[base + r + 1] = dbQ;
                if (nv == 3) { oc[base + r] = dcP; oc[base + r + 1] = dcQ; }
            }
        }
    } else if (blk < 87) {
        int job = blk - 72;
        const float *a, *bvec; float bias; float* out;
        if (job < 3)      { int i = job;     a = bq + i * D; bvec = mu_w + i * D;  bias = mu_b[i];  out = ws + OFF_CMU + i; }
        else if (job < 6) { int i = job - 3; a = bq + i * D; bvec = lv_w + i * D;  bias = lv_b[i];  out = ws + OFF_CLV + i; }
        else if (job < 9) { int i = job - 6; a = bq + i * D; bvec = pgq_w + i * D; bias = pgq_b[i]; out = ws + OFF_CPGQ + i; }
        else {
            int p = job - 9, i = p / 2, c = p % 2, j = c + (c >= i ? 1 : 0);
            a = bk + j * D; bvec = pgk_w + i * D; bias = pgk_b[i]; out = ws + OFF_CPK + p;
        }
        int t = threadIdx.x;
        float part = 0.f;
        if (t < 192) part = dot4(((const float4*)a)[t], ((const float4*)bvec)[t]);
        part = wave_reduce(part);
        __shared__ float r[4];
        if ((t & 63) == 0) r[t >> 6] = part;
        __syncthreads();
        if (t == 0) *out = r[0] + r[1] + r[2] + r[3] + bias;
    } else if (blk < 519) {
        int r = blk - 87;
        int j = r / 144; r = r % 144;
        int d0 = (r / 12) * 64, e0 = (r % 12) * 64;
        __shared__ float tile[64][65];
        const float* src = Wk + j * D * D;
        for (int idx = threadIdx.x; idx < 4096; idx += 256) {
            int rr = idx / 64, cc = idx % 64;
            tile[rr][cc] = src[(d0 + rr) * D + e0 + cc];
        }
        __syncthreads();
        float* dst = ws + OFF_WKT + j * D * D;
        for (int idx = threadIdx.x; idx < 4096; idx += 256) {
            int rr = idx / 64, cc = idx % 64;
            dst[(e0 + rr) * D + d0 + cc] = tile[cc][rr];
        }
    } else {
        // Q partials: blocks (i 3, bg 2 (16 b), kc 24 (32 k)) = 144
        int qb = blk - 519;
        int i = qb / 48, r = qb % 48, bg = r / 24, kc = r % 24;
        int kbase = kc * 32;
        __shared__ __align__(16) float xs[32][16];
        for (int idx = threadIdx.x; idx < 512; idx += 256) {
            int d = idx & 31, bb = idx >> 5;
            xs[d][bb] = feats[((size_t)(i * B + bg * 16 + bb) * S) * D + kbase + d];
        }
        __syncthreads();
        if (threadIdx.x < 192) {
            GEMV16_BODY(Wq + i * D * D + kbase * D + threadIdx.x * 4,
                        OFF_ARENA + kc * 73728, (i * 32 + bg * 16))
        }
    }
}

// L1b: reduce Q partials (+bq) -> OFF_Q, qbk = Q.bk, and PQ gate from feats row 0. 96 blocks (i,b).
__global__ __launch_bounds__(256) void k_redQ(const float* feats, const float* bq,
        const float* bk, const float* eps, const float* dyn, float* ws) {
    int blk = blockIdx.x;
    int i = blk / B, b = blk % B;
    int fbase = (i * B + b) * D;
    int t = threadIdx.x;
    int wave = t >> 6, lane = t & 63;
    __shared__ float4 qsh[192];
    __shared__ float redsh[8];
    __shared__ float pqred[12];
    if (t < 192) {
        float4 a = *(const float4*)&bq[i * D + t * 4];
        #pragma unroll
        for (int kc = 0; kc < 24; kc++) {
            float4 v = *(const float4*)&ws[OFF_ARENA + kc * 73728 + fbase + t * 4];
            a.x += v.x; a.y += v.y; a.z += v.z; a.w += v.w;
        }
        *(float4*)&ws[OFF_Q + fbase + t * 4] = a;
        qsh[t] = a;
    }
    __syncthreads();
    int jA = (i == 0) ? 1 : 0, jB = (i == 2) ? 1 : 2;
    float pA_ = 0.f, pB_ = 0.f;
    if (t < 192) {
        float4 q = qsh[t];
        pA_ = dot4(q, *(const float4*)&bk[jA * D + t * 4]);
        pB_ = dot4(q, *(const float4*)&bk[jB * D + t * 4]);
    }
    pA_ = wave_reduce(pA_); pB_ = wave_reduce(pB_);
    if (lane == 0) { redsh[wave] = pA_; redsh[4 + wave] = pB_; }
    float dm = 0.f, dl = 0.f, dp = 0.f;
    if (t < 192) {
        float4 x = *(const float4*)&feats[((size_t)(i * B + b) * S) * D + t * 4];
        dm = dot4(x, *(const float4*)&ws[OFF_WMU + i * D + t * 4]);
        dl = dot4(x, *(const float4*)&ws[OFF_WLV + i * D + t * 4]);
        dp = dot4(x, *(const float4*)&ws[OFF_WPGQ + i * D + t * 4]);
    }
    dm = wave_reduce(dm); dl = wave_reduce(dl); dp = wave_reduce(dp);
    if (lane == 0 && wave < 3) { pqred[wave] = dm; pqred[4 + wave] = dl; pqred[8 + wave] = dp; }
    __syncthreads();
    if (t == 0) {
        ws[OFF_QBK + (2 * i) * B + b]     = redsh[0] + redsh[1] + redsh[2] + redsh[3];
        ws[OFF_QBK + (2 * i + 1) * B + b] = redsh[4] + redsh[5] + redsh[6] + redsh[7];
        float mu0 = pqred[0] + pqred[1] + pqred[2] + ws[OFF_CMU + i];
        float lv0 = pqred[4] + pqred[5] + pqred[6] + ws[OFF_CLV + i];
        float pqb = pqred[8] + pqred[9] + pqred[10] + ws[OFF_CPGQ + i];
        float sd = dyn[0] * __expf(0.5f * lv0);
        float pqs = sigmoidf(pqb);
        #pragma unroll
        for (int c = 0; c < 2; c++) {
            int p = 2 * i + c;
            float e0 = eps[(size_t)(p * B + b) * S];
            ws[OFF_PQ + p * B + b] = pqs * sigmoidf(mu0 + sd * e0);
        }
    }
}

// L2: qk GEMV (bb=16) + Q@Wqc partials (moved off critical path).
// blocks 0..287: qk (j 3, vg 4 (16 v), kc 24); 288..431: Wqc (i 3, bg 2, kc 24). 192 thr.
__global__ __launch_bounds__(192, 4) void k_qk(const float* Wqc_w, float* ws) {
    int blk = blockIdx.x;
    __shared__ __align__(16) float xs[32][16];
    if (blk < 288) {
        int j = blk / 96, r = blk % 96, vg = r / 24, kc = r % 24;
        int kbase = kc * 32;
        int i1 = (j == 0) ? 1 : 0, i2 = (j == 2) ? 1 : 2;
        for (int idx = threadIdx.x; idx < 512; idx += 192) {
            int d = idx & 31, v = idx >> 5;
            int v16 = vg * 16 + v;
            int i_ = (v16 < 32) ? i1 : i2, b = v16 & 31;
            xs[d][v] = ws[OFF_Q + (i_ * 32 + b) * 768 + kbase + d];
        }
        __syncthreads();
        if (threadIdx.x < 192) {
            GEMV16_BODY(ws + OFF_WKT + j * D * D + kbase * D + threadIdx.x * 4,
                        OFF_ARENA2 + kc * 147456, (j * 64 + vg * 16))
        }
    } else {
        int q2 = blk - 288;
        int i = q2 / 48, r2 = q2 % 48, bg = r2 / 24, kc = r2 % 24;
        int kbase = kc * 32;
        for (int idx = threadIdx.x; idx < 512; idx += 192) {
            int d = idx & 31, v = idx >> 5;
            xs[d][v] = ws[OFF_Q + (i * B + bg * 16 + v) * 768 + kbase + d];
        }
        __syncthreads();
        if (threadIdx.x < 192) {
            GEMV16_BODY(Wqc_w + i * D * D + kbase * D + threadIdx.x * 4,
                        OFF_ARENA2 + (48 + kc) * 73728, (i * 32 + bg * 16))
        }
    }
}

// L2b: coalesced reduce of qk partials (24 slots) -> QK[p][b][d]. 144 blocks x 256.
__global__ __launch_bounds__(256) void k_redqk(float* ws) {
    int idx = blockIdx.x * 256 + threadIdx.x;
    int fidx = idx * 4;
    int row = fidx / 768;
    int j = row / 64, v64 = row % 64;
    int b = v64 & 31, islot = v64 >> 5;
    int i_ = islot ? ((j == 2) ? 1 : 2) : ((j == 0) ? 1 : 0);
    int p = 2 * i_ + ((j < i_) ? j : j - 1);
    int d = fidx % 768;
    float4 a = make_float4(0.f, 0.f, 0.f, 0.f);
    #pragma unroll
    for (int kc = 0; kc < 24; kc++) {
        float4 v = *(const float4*)&ws[OFF_ARENA2 + kc * 147456 + fidx];
        a.x += v.x; a.y += v.y; a.z += v.z; a.w += v.w;
    }
    *(float4*)&ws[OFF_QK + (p * B + b) * D + d] = a;
}

// L3: MEGA-FUSED single feats pass. 256 blocks (b 32, h 8) x 1024 threads.
__global__ __launch_bounds__(1024) void k_fused(const float* feats, const float* eps,
                                                const float* dyn, float* ws) {
    int blk = blockIdx.x;
    int b = blk >> 3, h = blk & 7;
    int t = threadIdx.x;
    int w = t >> 6, lane = t & 63;
    __shared__ __align__(16) float swA[4608];   // WMU[3][768] | WLV[3][768]
    __shared__ __align__(16) float swPK[4608];  // WPK[6][768]
    __shared__ __align__(16) float sqk[4608];   // qk[6][768]
    __shared__ float raws[6][32], pkps[6][32], mus[3][32], lvs[3][32], wgt[6][32];
    __shared__ float klv[96];
    __shared__ float pq_s[6], qbk_s[6], cmu_s[3], clv_s[3], cpk_s[6];
    {
        const float4* srcA = (const float4*)(ws + OFF_WMU);
        const float4* srcP = (const float4*)(ws + OFF_WPK);
        float4* dA = (float4*)swA;
        float4* dP = (float4*)swPK;
        float4* dQ = (float4*)sqk;
        for (int idx = t; idx < 1152; idx += 1024) {
            dA[idx] = srcA[idx];
            dP[idx] = srcP[idx];
            int p = idx / 192, d4 = (idx % 192) * 4;
            dQ[idx] = *(const float4*)&ws[OFF_QK + (p * B + b) * D + d4];
        }
        if (t < 6) { pq_s[t] = ws[OFF_PQ + t * B + b]; qbk_s[t] = ws[OFF_QBK + t * B + b]; cpk_s[t] = ws[OFF_CPK + t]; }
        else if (t < 9) { cmu_s[t - 6] = ws[OFF_CMU + t - 6]; clv_s[t - 6] = ws[OFF_CLV + t - 6]; }
    }
    __syncthreads();
    const float4* swA4 = (const float4*)swA;
    const float4* swPK4 = (const float4*)swPK;
    const float4* sqk4 = (const float4*)sqk;
    for (int tau = w * 6; tau < w * 6 + 6; tau++) {
        int m = tau >> 5, k = tau & 31;
        const float4* row = (const float4*)(feats + ((size_t)((m * B + b) * S) + h * 32 + k) * D);
        float4 x0 = row[lane], x1 = row[lane + 64], x2 = row[lane + 128];
        int i1 = (m == 0) ? 1 : 0, i2 = (m == 2) ? 1 : 2;
        int pj0 = 2 * i1 + ((m < i1) ? m : m - 1);
        int pj1 = 2 * i2 + ((m < i2) ? m : m - 1);
        int oM = m * 192, oL = (3 + m) * 192, o0 = pj0 * 192, o1 = pj1 * 192;
        float dmu = dot4(x0, swA4[oM + lane]) + dot4(x1, swA4[oM + lane + 64]) + dot4(x2, swA4[oM + lane + 128]);
        float dlv = dot4(x0, swA4[oL + lane]) + dot4(x1, swA4[oL + lane + 64]) + dot4(x2, swA4[oL + lane + 128]);
        float dk0 = dot4(x0, swPK4[o0 + lane]) + dot4(x1, swPK4[o0 + lane + 64]) + dot4(x2, swPK4[o0 + lane + 128]);
        float dk1 = dot4(x0, swPK4[o1 + lane]) + dot4(x1, swPK4[o1 + lane + 64]) + dot4(x2, swPK4[o1 + lane + 128]);
        float dr0 = dot4(x0, sqk4[o0 + lane]) + dot4(x1, sqk4[o0 + lane + 64]) + dot4(x2, sqk4[o0 + lane + 128]);
        float dr1 = dot4(x0, sqk4[o1 + lane]) + dot4(x1, sqk4[o1 + lane + 64]) + dot4(x2, sqk4[o1 + lane + 128]);
        dmu = wave_reduce(dmu); dlv = wave_reduce(dlv);
        dk0 = wave_reduce(dk0); dk1 = wave_reduce(dk1);
        dr0 = wave_reduce(dr0); dr1 = wave_reduce(dr1);
        if (lane == 0) {
            mus[m][k] = dmu + cmu_s[m];
            lvs[m][k] = dlv + clv_s[m];
            pkps[pj0][k] = dk0 + cpk_s[pj0];
            pkps[pj1][k] = dk1 + cpk_s[pj1];
            raws[pj0][k] = dr0;
            raws[pj1][k] = dr1;
        }
    }
    __syncthreads();
    float dynv = dyn[0];
    if (t < 192) {
        int p = t >> 5, k = t & 31;
        int iq = p >> 1;
        float e = eps[(size_t)(p * B + b) * S + h * 32 + k];
        float g = sigmoidf(mus[iq][k] + dynv * __expf(0.5f * lvs[iq][k]) * e);
        float pk = sigmoidf(pkps[p][k]) * g;
        float s = (raws[p][k] + qbk_s[p]) * SCALE * pq_s[p] * pk;
        float mc = s;
        #pragma unroll
        for (int o = 16; o > 0; o >>= 1) mc = fmaxf(mc, __shfl_xor(mc, o, 64));
        float wv_ = __expf(s - mc);
        float l = wv_;
        #pragma unroll
        for (int o = 16; o > 0; o >>= 1) l += __shfl_xor(l, o, 64);
        wgt[p][k] = wv_;
        if (k == 0) {
            float* mh = ws + OFF_MLH + (p * B + b) * 16 + h * 2;
            mh[0] = mc; mh[1] = l;
        }
    } else if (t < 288) {
        int tau = t - 192;
        int m = tau >> 5, k = tau & 31;
        float muv = mus[m][k], lvv = lvs[m][k];
        klv[tau] = 1.0f + lvv - muv * muv - __expf(lvv);
    }
    __syncthreads();
    if (t < 768) {
        #pragma unroll
        for (int jm = 0; jm < 3; jm++) {
            int i1 = (jm == 0) ? 1 : 0, i2 = (jm == 2) ? 1 : 2;
            int pj0 = 2 * i1 + ((jm < i1) ? jm : jm - 1);
            int pj1 = 2 * i2 + ((jm < i2) ? jm : jm - 1);
            const float* col = feats + ((size_t)((jm * B + b) * S) + h * 32) * D + t;
            float accA = 0.f, accB = 0.f;
            #pragma unroll 8
            for (int k = 0; k < 32; k++) {
                float fv = col[(size_t)k * D];
                accA += wgt[pj0][k] * fv;
                accB += wgt[pj1][k] * fv;
            }
            ws[OFF_FSUM + h * 147456 + (pj0 * B + b) * D + t] = accA;
            ws[OFF_FSUM + h * 147456 + (pj1 * B + b) * D + t] = accB;
        }
    }
    if (t < 64) {
        float s2 = klv[t] + ((t < 32) ? klv[64 + t] : 0.f);
        s2 = wave_reduce(s2);
        if (t == 0) ws[OFF_KLP + blk] = s2;
    }
}

// L4: agg partials (bb=16), combining 8 S-chunks via (m,l).
// 288 blocks (i 3, js 2, bg 2, kc 24) x 192.
__global__ __launch_bounds__(192, 3) void k_agg2(const float* Wv, float* ws) {
    int blk = blockIdx.x;
    int i = blk / 96, r = blk % 96, js = r / 48, r2 = r % 48, bg = r2 / 24, kc = r2 % 24;
    int kbase = kc * 32;
    int j0 = (i == 0) ? 1 : 0, j1 = (i == 2) ? 1 : 2;
    int jv = js ? j1 : j0;
    int p = 2 * i + js;
    __shared__ __align__(16) float xs[32][16];
    __shared__ float comb[8][16];
    if (threadIdx.x < 16) {
        int bb = threadIdx.x;
        const float* mh = ws + OFF_MLH + (p * B + bg * 16 + bb) * 16;
        float mm[8], ll[8];
        float mx = -1e30f;
        #pragma unroll
        for (int hh = 0; hh < 8; hh++) { mm[hh] = mh[2 * hh]; ll[hh] = mh[2 * hh + 1]; mx = fmaxf(mx, mm[hh]); }
        float L = 0.f;
        float ee[8];
        #pragma unroll
        for (int hh = 0; hh < 8; hh++) { ee[hh] = __expf(mm[hh] - mx); L += ee[hh] * ll[hh]; }
        #pragma unroll
        for (int hh = 0; hh < 8; hh++) comb[hh][bb] = ee[hh] / L;
    }
    __syncthreads();
    for (int idx = threadIdx.x; idx < 512; idx += 192) {
        int d = idx & 31, bb = idx >> 5;
        int base = OFF_FSUM + (p * B + bg * 16 + bb) * D + kbase + d;
        float v = 0.f;
        #pragma unroll
        for (int hh = 0; hh < 8; hh++) v += comb[hh][bb] * ws[base + hh * 147456];
        xs[d][bb] = v;
    }
    __syncthreads();
    if (threadIdx.x < 192) {
        GEMV16_BODY(Wv + jv * D * D + kbase * D + threadIdx.x * 4,
                    OFF_ARENA + (js * 24 + kc) * 73728, (i * 32 + bg * 16))
    }
}

// L4b: coalesced reduce agg partials (48 slots) + bv biases -> AGG. 72 blocks x 256.
__global__ __launch_bounds__(256) void k_redA(const float* bv, float* ws) {
    int idx = blockIdx.x * 256 + threadIdx.x;
    int fidx = idx * 4;
    int i = fidx / 24576, e = fidx % 768;
    int j0 = (i == 0) ? 1 : 0, j1 = (i == 2) ? 1 : 2;
    float4 b0 = *(const float4*)&bv[j0 * 768 + e];
    float4 b1 = *(const float4*)&bv[j1 * 768 + e];
    float4 a = make_float4(b0.x + b1.x, b0.y + b1.y, b0.z + b1.z, b0.w + b1.w);
    #pragma unroll
    for (int s = 0; s < 48; s++) {
        float4 p = *(const float4*)&ws[OFF_ARENA + s * 73728 + fidx];
        a.x += p.x; a.y += p.y; a.z += p.z; a.w += p.w;
    }
    *(float4*)&ws[OFF_AGG + fidx] = a;
}

// L5: E/G partials from AGG (bb=16). 288 blocks (kind 2, i 3, bg 2, kc 24) x 192.
// kind0: E = AGG@WE (slots 0..23); kind1: G partial = AGG@Wh (slots 24..47).
// (Q@Wqc partials were produced earlier by k_qk into slots 48..71.)
__global__ __launch_bounds__(192, 4) void k_eg2(const float* WE_w, const float* Wh_w,
                                                float* ws) {
    int blk = blockIdx.x;
    int kind = blk / 144, r = blk % 144;
    int i = r / 48, r2 = r % 48, bg = r2 / 24, kc = r2 % 24;
    int kbase = kc * 32;
    __shared__ __align__(16) float xs[32][16];
    for (int idx = threadIdx.x; idx < 512; idx += 192) {
        int d = idx & 31, bb = idx >> 5;
        xs[d][bb] = ws[OFF_AGG + (i * 32 + bg * 16 + bb) * 768 + kbase + d];
    }
    __syncthreads();
    if (threadIdx.x < 192) {
        GEMV16_BODY(((kind == 0) ? WE_w : Wh_w) + i * D * D + kbase * D + threadIdx.x * 4,
                    OFF_ARENA2 + (kind * 24 + kc) * 73728, (i * 32 + bg * 16))
    }
}

// L5b+L6 merged: reduce E/G partials (+bias+relu), then LayerNorm(E)*LayerNorm(G)
// -> FUSED. 96 blocks (i,b) x 256.
__global__ __launch_bounds__(256) void k_redEGLN(const float* WE_b, const float* Wh_b,
        const float* Wqc_b,
        const float* lnE_g, const float* lnE_b,
        const float* lnG_g, const float* lnG_b, float* ws) {
    int blk = blockIdx.x;
    int i = blk / B, b = blk % B;
    int row = (i * B + b) * D;
    int t = threadIdx.x;
    float4 e = make_float4(0.f, 0.f, 0.f, 0.f);
    float4 g = make_float4(0.f, 0.f, 0.f, 0.f);
    if (t < 192) {
        e = *(const float4*)&WE_b[i * D + t * 4];
        float4 b0 = *(const float4*)&Wh_b[i * D + t * 4];
        float4 b1 = *(const float4*)&Wqc_b[i * D + t * 4];
        g = make_float4(b0.x + b1.x, b0.y + b1.y, b0.z + b1.z, b0.w + b1.w);
        #pragma unroll
        for (int s = 0; s < 24; s++) {
            float4 p = *(const float4*)&ws[OFF_ARENA2 + s * 73728 + row + t * 4];
            e.x += p.x; e.y += p.y; e.z += p.z; e.w += p.w;
        }
        #pragma unroll
        for (int s = 24; s < 72; s++) {
            float4 p = *(const float4*)&ws[OFF_ARENA2 + s * 73728 + row + t * 4];
            g.x += p.x; g.y += p.y; g.z += p.z; g.w += p.w;
        }
        e.x = fmaxf(e.x, 0.f); e.y = fmaxf(e.y, 0.f); e.z = fmaxf(e.z, 0.f); e.w = fmaxf(e.w, 0.f);
        g.x = fmaxf(g.x, 0.f); g.y = fmaxf(g.y, 0.f); g.z = fmaxf(g.z, 0.f); g.w = fmaxf(g.w, 0.f);
    }
    __shared__ float r1[256], r2[256], r3[256], r4[256];
    r1[t] = e.x + e.y + e.z + e.w;
    r2[t] = e.x * e.x + e.y * e.y + e.z * e.z + e.w * e.w;
    r3[t] = g.x + g.y + g.z + g.w;
    r4[t] = g.x * g.x + g.y * g.y + g.z * g.z + g.w * g.w;
    __syncthreads();
    for (int st = 128; st > 0; st >>= 1) {
        if (t < st) { r1[t] += r1[t + st]; r2[t] += r2[t + st]; r3[t] += r3[t + st]; r4[t] += r4[t + st]; }
        __syncthreads();
    }
    float mE = r1[0] * (1.0f / D), vE = r2[0] * (1.0f / D) - mE * mE;
    float mG = r3[0] * (1.0f / D), vG = r4[0] * (1.0f / D) - mG * mG;
    float sE = rsqrtf(vE + LN_EPS), sG = rsqrtf(vG + LN_EPS);
    if (t < 192) {
        float4 eg  = *(const float4*)&lnE_g[i * D + t * 4];
        float4 ebv = *(const float4*)&lnE_b[i * D + t * 4];
        float4 gg  = *(const float4*)&lnG_g[i * D + t * 4];
        float4 gbv = *(const float4*)&lnG_b[i * D + t * 4];
        float4 o;
        o.x = ((e.x - mE) * sE * eg.x + ebv.x) * ((g.x - mG) * sG * gg.x + gbv.x);
        o.y = ((e.y - mE) * sE * eg.y + ebv.y) * ((g.y - mG) * sG * gg.y + gbv.y);
        o.z = ((e.z - mE) * sE * eg.z + ebv.z) * ((g.z - mG) * sG * gg.z + gbv.z);
        o.w = ((e.w - mE) * sE * eg.w + ebv.w) * ((g.w - mG) * sG * gg.w + gbv.w);
        *(float4*)&ws[OFF_FUSED + b * MD + i * D + t * 4] = o;
    }
}

// L7: out GEMM partials (bb=16) -> arena. 144 blocks (bg 2, kc 72 (32 k)) x 256.
__global__ __launch_bounds__(256, 4) void k_out2(const float* out_w, float* ws) {
    int blk = blockIdx.x;
    int bg = blk / 72, kc = blk % 72;
    int kbase = kc * 32;
    __shared__ __align__(16) float xs[32][16];
    for (int idx = threadIdx.x; idx < 512; idx += 256) {
        int d = idx & 31, bb = idx >> 5;
        xs[d][bb] = ws[OFF_FUSED + (bg * 16 + bb) * MD + kbase + d];
    }
    __syncthreads();
    int e4 = threadIdx.x * 4;
    const float* Wm = out_w + kbase * H + e4;
    float4 acc[16];
    #pragma unroll
    for (int v = 0; v < 16; v++) acc[v] = make_float4(0.f, 0.f, 0.f, 0.f);
    for (int k = 0; k < 32; k++) {
        float4 w = *(const float4*)(Wm + k * H);
        float4 x0 = *(const float4*)&xs[k][0];
        float4 x1 = *(const float4*)&xs[k][4];
        float4 x2 = *(const float4*)&xs[k][8];
        float4 x3 = *(const float4*)&xs[k][12];
        fma4(acc[0], x0.x, w);  fma4(acc[1], x0.y, w);
        fma4(acc[2], x0.z, w);  fma4(acc[3], x0.w, w);
        fma4(acc[4], x1.x, w);  fma4(acc[5], x1.y, w);
        fma4(acc[6], x1.z, w);  fma4(acc[7], x1.w, w);
        fma4(acc[8], x2.x, w);  fma4(acc[9], x2.y, w);
        fma4(acc[10], x2.z, w); fma4(acc[11], x2.w, w);
        fma4(acc[12], x3.x, w); fma4(acc[13], x3.y, w);
        fma4(acc[14], x3.z, w); fma4(acc[15], x3.w, w);
    }
    #pragma unroll
    for (int v = 0; v < 16; v++)
        *(float4*)&ws[OFF_ARENA + kc * 32768 + (bg * 16 + v) * 1024 + e4] = acc[v];
}

// L7b: sum out partials (72 kc) + bias; block 0 reduces KL partials (256). 32 blocks (b) x 256.
__global__ __launch_bounds__(256) void k_fin(const float* out_b, float* ws, float* out) {
    int b = blockIdx.x;
    int h4 = threadIdx.x * 4;
    float4 a = *(const float4*)&out_b[h4];
    #pragma unroll
    for (int kc = 0; kc < 72; kc++) {
        float4 p = *(const float4*)&ws[OFF_ARENA + kc * 32768 + b * 1024 + h4];
        a.x += p.x; a.y += p.y; a.z += p.z; a.w += p.w;
    }
    *(float4*)&out[b * H + h4] = a;
    if (b == 0) {
        int t = threadIdx.x;
        __shared__ float kls[256];
        kls[t] = ws[OFF_KLP + t];
        __syncthreads();
        for (int st = 128; st > 0; st >>= 1) {
            if (t < st) kls[t] += kls[t + st];
            __syncthreads();
        }
        if (t == 0) out[B * H] = -kls[0];
    }
}

extern "C" void kernel_launch(void* const* d_in, const int* in_sizes, int n_in,
                              void* d_out, int out_size, void* d_ws, size_t ws_size,
                              hipStream_t stream) {
    const float* feats = (const float*)d_in[0];
    const float* Wq    = (const float*)d_in[1];
    const float* bq    = (const float*)d_in[2];
    const float* Wk    = (const float*)d_in[3];
    const float* bk    = (const float*)d_in[4];
    const float* Wv    = (const float*)d_in[5];
    const float* bv    = (const float*)d_in[6];
    const float* pgq_w = (const float*)d_in[7];
    const float* pgq_b = (const float*)d_in[8];
    const float* pgk_w = (const float*)d_in[9];
    const float* pgk_b = (const float*)d_in[10];
    const float* mu_w  = (const float*)d_in[11];
    const float* mu_b  = (const float*)d_in[12];
    const float* lv_w  = (const float*)d_in[13];
    const float* lv_b  = (const float*)d_in[14];
    const float* dyn   = (const float*)d_in[15];
    const float* WE_w  = (const float*)d_in[16];
    const float* WE_b  = (const float*)d_in[17];
    const float* Wh_w  = (const float*)d_in[18];
    const float* Wh_b  = (const float*)d_in[19];
    const float* Wqc_w = (const float*)d_in[20];
    const float* Wqc_b = (const float*)d_in[21];
    const float* lnE_g = (const float*)d_in[22];
    const float* lnE_b = (const float*)d_in[23];
    const float* lnG_g = (const float*)d_in[24];
    const float* lnG_b = (const float*)d_in[25];
    const float* out_w = (const float*)d_in[26];
    const float* out_b = (const float*)d_in[27];
    const float* eps   = (const float*)d_in[28];
    float* ws  = (float*)d_ws;
    float* out = (float*)d_out;

    k_prep2<<<663, 256, 0, stream>>>(feats, Wq, Wk, bq, bk, mu_w, mu_b, lv_w, lv_b,
                                     pgq_w, pgq_b, pgk_w, pgk_b, ws);
    k_redQ<<<96, 256, 0, stream>>>(feats, bq, bk, eps, dyn, ws);
    k_qk<<<432, 192, 0, stream>>>(Wqc_w, ws);
    k_redqk<<<144, 256, 0, stream>>>(ws);
    k_fused<<<256, 1024, 0, stream>>>(feats, eps, dyn, ws);
    k_agg2<<<288, 192, 0, stream>>>(Wv, ws);
    k_redA<<<72, 256, 0, stream>>>(bv, ws);
    k_eg2<<<288, 192, 0, stream>>>(WE_w, Wh_w, ws);
    k_redEGLN<<<96, 256, 0, stream>>>(WE_b, Wh_b, Wqc_b, lnE_g, lnE_b, lnG_g, lnG_b, ws);
    k_out2<<<144, 256, 0, stream>>>(out_w, ws);
    k_fin<<<32, 256, 0, stream>>>(out_b, ws, out);
}

// Round 9
// 302.078 us; speedup vs baseline: 1.0409x; 1.0409x over previous
//
#include <hip/hip_runtime.h>

// Problem constants (fixed by the reference)
#define M 3
#define B 32
#define S 256
#define D 768
#define H 1024
#define MD (M * D)          // 2304
#define NP (M * (M - 1))    // 6 ordered (i,j) pairs
#define SCALE 0.03608439182435161f  // 1/sqrt(768)
#define LN_EPS 1e-5f

// Workspace layout (float offsets). ws is ~302 MB; we use ~85 MB.
#define OFF_WMU   0         // [M][D]
#define OFF_WLV   2304      // [M][D]
#define OFF_WPGQ  4608      // [M][D]
#define OFF_WPK   6912      // [NP][D]
#define OFF_CMU   11520     // [M]
#define OFF_CLV   11523     // [M]
#define OFF_CPGQ  11526     // [M]
#define OFF_CPK   11529     // [NP]
#define OFF_PQ    11536     // [NP][B] final pq gate (pq_base * g0)
#define OFF_Q     11776     // [M][B][D]
#define OFF_QBK   85504     // [NP][B]
#define OFF_QK    85760     // [NP][B][D] reduced qk (147456)
#define OFF_MLH   233216    // [NP][B][8(h)][2(m,l)] = 3072
#define OFF_KLP   236288    // [256] per-block KL partials
#define OFF_AGG   236544    // [M][B][D]
#define OFF_FUSED 457728    // [B][MD]
#define OFF_FSUM  531520    // [8(h)][NP][B][D] (h stride 147456) = 1179648
#define OFF_WKT   1711168   // [M][D][D] Wk transposed (1769472)
#define OFF_ARENA 3480640   // 96 slots x 73728: Q partials (48) -> agg partials (96) -> out partials (72 x 32768)
#define OFF_ARENA2 10558528 // qk partials (48 x 147456) -> E/G partials (96 x 73728)
#define OFF_WQC   17636416  // Wqc partials (48 x 73728)

__device__ __forceinline__ float wave_reduce(float v) {
    #pragma unroll
    for (int o = 32; o > 0; o >>= 1) v += __shfl_down(v, o, 64);
    return v;
}

__device__ __forceinline__ float sigmoidf(float x) {
    return 1.0f / (1.0f + __expf(-x));
}

__device__ __forceinline__ float dot4(float4 a, float4 b) {
    return a.x * b.x + a.y * b.y + a.z * b.z + a.w * b.w;
}

__device__ __forceinline__ void fma4(float4& a, float s, float4 w) {
    a.x += s * w.x; a.y += s * w.y; a.z += s * w.z; a.w += s * w.w;
}

// 8-row, K=16 GEMV core: xs[16][8] in LDS, thread owns float4 of e, acc[8].
#define GEMV8_K16(WPTR, OUTBASE, ROWBASE_EXPR)                                     \
    {                                                                              \
        int e4 = threadIdx.x * 4;                                                  \
        const float* Wm = (WPTR);                                                  \
        float4 acc[8];                                                             \
        _Pragma("unroll")                                                          \
        for (int v = 0; v < 8; v++) acc[v] = make_float4(0.f, 0.f, 0.f, 0.f);      \
        _Pragma("unroll")                                                          \
        for (int k = 0; k < 16; k++) {                                             \
            float4 w = *(const float4*)(Wm + k * D);                               \
            float4 x0 = *(const float4*)&xs[k][0];                                 \
            float4 x1 = *(const float4*)&xs[k][4];                                 \
            fma4(acc[0], x0.x, w); fma4(acc[1], x0.y, w);                          \
            fma4(acc[2], x0.z, w); fma4(acc[3], x0.w, w);                          \
            fma4(acc[4], x1.x, w); fma4(acc[5], x1.y, w);                          \
            fma4(acc[6], x1.z, w); fma4(acc[7], x1.w, w);                          \
        }                                                                          \
        _Pragma("unroll")                                                          \
        for (int v = 0; v < 8; v++)                                                \
            *(float4*)&ws[(OUTBASE) + (ROWBASE_EXPR + v) * 768 + e4] = acc[v];     \
    }

// L1: fused prep + Q partials (bb=8, split-K 48).
// blocks 0..71 vector-dots, 72..86 scalar consts, 87..518 Wk transpose,
// 519..1094 Q GEMV partials (i 3, bg 4 (8 b), kc 48 (16 k)).
__global__ __launch_bounds__(256) void k_prep2(const float* feats,
        const float* Wq, const float* Wk,
        const float* bq, const float* bk,
        const float* mu_w, const float* mu_b, const float* lv_w, const float* lv_b,
        const float* pgq_w, const float* pgq_b, const float* pgk_w, const float* pgk_b,
        float* ws) {
    int blk = blockIdx.x;
    if (blk < 72) {
        int mat = blk / 12, rg = blk % 12;
        const float* Wm; const float *va, *vb, *vc;
        float *oa, *ob, *oc; int nv;
        if (mat < 3) {
            int i = mat;
            Wm = Wq + i * D * D;
            va = mu_w + i * D; vb = lv_w + i * D; vc = pgq_w + i * D;
            oa = ws + OFF_WMU + i * D; ob = ws + OFF_WLV + i * D; oc = ws + OFF_WPGQ + i * D;
            nv = 3;
        } else {
            int j = mat - 3;
            int i1 = (j == 0) ? 1 : 0, i2 = (j == 2) ? 1 : 2;
            int p1 = 2 * i1 + ((j < i1) ? j : j - 1);
            int p2 = 2 * i2 + ((j < i2) ? j : j - 1);
            Wm = Wk + j * D * D;
            va = pgk_w + i1 * D; vb = pgk_w + i2 * D; vc = va;
            oa = ws + OFF_WPK + p1 * D; ob = ws + OFF_WPK + p2 * D; oc = oa;
            nv = 2;
        }
        int wave = threadIdx.x >> 6, lane = threadIdx.x & 63;
        const float4* va4 = (const float4*)va;
        const float4* vb4 = (const float4*)vb;
        const float4* vc4 = (const float4*)vc;
        float4 A0 = va4[lane], A1 = va4[lane + 64], A2 = va4[lane + 128];
        float4 B0 = vb4[lane], B1 = vb4[lane + 64], B2 = vb4[lane + 128];
        float4 C0 = vc4[lane], C1 = vc4[lane + 64], C2 = vc4[lane + 128];
        int base = rg * 64 + wave * 16;
        for (int r = 0; r < 16; r += 2) {
            const float4* rowP = (const float4*)(Wm + (base + r) * D);
            const float4* rowQ = (const float4*)(Wm + (base + r + 1) * D);
            float4 x0 = rowP[lane], x1 = rowP[lane + 64], x2 = rowP[lane + 128];
            float4 y0 = rowQ[lane], y1 = rowQ[lane + 64], y2 = rowQ[lane + 128];
            float daP = dot4(x0, A0) + dot4(x1, A1) + dot4(x2, A2);
            float dbP = dot4(x0, B0) + dot4(x1, B1) + dot4(x2, B2);
            float dcP = dot4(x0, C0) + dot4(x1, C1) + dot4(x2, C2);
            float daQ = dot4(y0, A0) + dot4(y1, A1) + dot4(y2, A2);
            float dbQ = dot4(y0, B0) + dot4(y1, B1) + dot4(y2, B2);
            float dcQ = dot4(y0, C0) + dot4(y1, C1) + dot4(y2, C2);
            daP = wave_reduce(daP); dbP = wave_reduce(dbP);
            daQ = wave_reduce(daQ); dbQ = wave_reduce(dbQ);
            if (nv == 3) { dcP = wave_reduce(dcP); dcQ = wave_reduce(dcQ); }
            if (lane == 0) {
                oa[base + r] = daP; ob[base + r] = dbP;
                oa[base + r + 1] = daQ; ob[base + r + 1] = dbQ;
                if (nv == 3) { oc[base + r] = dcP; oc[base + r + 1] = dcQ; }
            }
        }
    } else if (blk < 87) {
        int job = blk - 72;
        const float *a, *bvec; float bias; float* out;
        if (job < 3)      { int i = job;     a = bq + i * D; bvec = mu_w + i * D;  bias = mu_b[i];  out = ws + OFF_CMU + i; }
        else if (job < 6) { int i = job - 3; a = bq + i * D; bvec = lv_w + i * D;  bias = lv_b[i];  out = ws + OFF_CLV + i; }
        else if (job < 9) { int i = job - 6; a = bq + i * D; bvec = pgq_w + i * D; bias = pgq_b[i]; out = ws + OFF_CPGQ + i; }
        else {
            int p = job - 9, i = p / 2, c = p % 2, j = c + (c >= i ? 1 : 0);
            a = bk + j * D; bvec = pgk_w + i * D; bias = pgk_b[i]; out = ws + OFF_CPK + p;
        }
        int t = threadIdx.x;
        float part = 0.f;
        if (t < 192) part = dot4(((const float4*)a)[t], ((const float4*)bvec)[t]);
        part = wave_reduce(part);
        __shared__ float r[4];
        if ((t & 63) == 0) r[t >> 6] = part;
        __syncthreads();
        if (t == 0) *out = r[0] + r[1] + r[2] + r[3] + bias;
    } else if (blk < 519) {
        int r = blk - 87;
        int j = r / 144; r = r % 144;
        int d0 = (r / 12) * 64, e0 = (r % 12) * 64;
        __shared__ float tile[64][65];
        const float* src = Wk + j * D * D;
        for (int idx = threadIdx.x; idx < 4096; idx += 256) {
            int rr = idx / 64, cc = idx % 64;
            tile[rr][cc] = src[(d0 + rr) * D + e0 + cc];
        }
        __syncthreads();
        float* dst = ws + OFF_WKT + j * D * D;
        for (int idx = threadIdx.x; idx < 4096; idx += 256) {
            int rr = idx / 64, cc = idx % 64;
            dst[(e0 + rr) * D + d0 + cc] = tile[cc][rr];
        }
    } else {
        // Q partials: blocks (i 3, bg 4 (8 b), kc 48 (16 k)) = 576
        int qb = blk - 519;
        int i = qb / 192, r = qb % 192, bg = r / 48, kc = r % 48;
        int kbase = kc * 16;
        __shared__ __align__(16) float xs[16][8];
        for (int idx = threadIdx.x; idx < 128; idx += 256) {
            int d = idx >> 3, bb = idx & 7;
            xs[d][bb] = feats[((size_t)(i * B + bg * 8 + bb) * S) * D + kbase + d];
        }
        __syncthreads();
        if (threadIdx.x < 192) {
            GEMV8_K16(Wq + i * D * D + kbase * D + threadIdx.x * 4,
                      OFF_ARENA + kc * 73728, (i * 32 + bg * 8))
        }
    }
}

// L1b: reduce Q partials (48 slots, +bq) -> OFF_Q, qbk = Q.bk, PQ gate. 96 blocks (i,b).
__global__ __launch_bounds__(256) void k_redQ(const float* feats, const float* bq,
        const float* bk, const float* eps, const float* dyn, float* ws) {
    int blk = blockIdx.x;
    int i = blk / B, b = blk % B;
    int fbase = (i * B + b) * D;
    int t = threadIdx.x;
    int wave = t >> 6, lane = t & 63;
    __shared__ float4 qsh[192];
    __shared__ float redsh[8];
    __shared__ float pqred[12];
    if (t < 192) {
        float4 a = *(const float4*)&bq[i * D + t * 4];
        #pragma unroll
        for (int kc = 0; kc < 48; kc++) {
            float4 v = *(const float4*)&ws[OFF_ARENA + kc * 73728 + fbase + t * 4];
            a.x += v.x; a.y += v.y; a.z += v.z; a.w += v.w;
        }
        *(float4*)&ws[OFF_Q + fbase + t * 4] = a;
        qsh[t] = a;
    }
    __syncthreads();
    int jA = (i == 0) ? 1 : 0, jB = (i == 2) ? 1 : 2;
    float pA_ = 0.f, pB_ = 0.f;
    if (t < 192) {
        float4 q = qsh[t];
        pA_ = dot4(q, *(const float4*)&bk[jA * D + t * 4]);
        pB_ = dot4(q, *(const float4*)&bk[jB * D + t * 4]);
    }
    pA_ = wave_reduce(pA_); pB_ = wave_reduce(pB_);
    if (lane == 0) { redsh[wave] = pA_; redsh[4 + wave] = pB_; }
    float dm = 0.f, dl = 0.f, dp = 0.f;
    if (t < 192) {
        float4 x = *(const float4*)&feats[((size_t)(i * B + b) * S) * D + t * 4];
        dm = dot4(x, *(const float4*)&ws[OFF_WMU + i * D + t * 4]);
        dl = dot4(x, *(const float4*)&ws[OFF_WLV + i * D + t * 4]);
        dp = dot4(x, *(const float4*)&ws[OFF_WPGQ + i * D + t * 4]);
    }
    dm = wave_reduce(dm); dl = wave_reduce(dl); dp = wave_reduce(dp);
    if (lane == 0 && wave < 3) { pqred[wave] = dm; pqred[4 + wave] = dl; pqred[8 + wave] = dp; }
    __syncthreads();
    if (t == 0) {
        ws[OFF_QBK + (2 * i) * B + b]     = redsh[0] + redsh[1] + redsh[2] + redsh[3];
        ws[OFF_QBK + (2 * i + 1) * B + b] = redsh[4] + redsh[5] + redsh[6] + redsh[7];
        float mu0 = pqred[0] + pqred[1] + pqred[2] + ws[OFF_CMU + i];
        float lv0 = pqred[4] + pqred[5] + pqred[6] + ws[OFF_CLV + i];
        float pqb = pqred[8] + pqred[9] + pqred[10] + ws[OFF_CPGQ + i];
        float sd = dyn[0] * __expf(0.5f * lv0);
        float pqs = sigmoidf(pqb);
        #pragma unroll
        for (int c = 0; c < 2; c++) {
            int p = 2 * i + c;
            float e0 = eps[(size_t)(p * B + b) * S];
            ws[OFF_PQ + p * B + b] = pqs * sigmoidf(mu0 + sd * e0);
        }
    }
}

// L2: qk GEMV (split-K 48) + Q@Wqc partials (off critical path).
// blocks 0..1151: qk (j 3, vg 8, kc 48); 1152..1727: Wqc (i 3, bg 4, kc 48). 256 thr.
__global__ __launch_bounds__(256, 4) void k_qk(const float* Wqc_w, float* ws) {
    int blk = blockIdx.x;
    __shared__ __align__(16) float xs[16][8];
    if (blk < 1152) {
        int j = blk / 384, r = blk % 384, vg = r / 48, kc = r % 48;
        int kbase = kc * 16;
        int i1 = (j == 0) ? 1 : 0, i2 = (j == 2) ? 1 : 2;
        for (int idx = threadIdx.x; idx < 128; idx += 256) {
            int d = idx >> 3, v = idx & 7;
            int v64 = vg * 8 + v;
            int i_ = (v64 < 32) ? i1 : i2, b = v64 & 31;
            xs[d][v] = ws[OFF_Q + (i_ * 32 + b) * 768 + kbase + d];
        }
        __syncthreads();
        if (threadIdx.x < 192) {
            GEMV8_K16(ws + OFF_WKT + j * D * D + kbase * D + threadIdx.x * 4,
                      OFF_ARENA2 + kc * 147456, (j * 64 + vg * 8))
        }
    } else {
        int q2 = blk - 1152;
        int i = q2 / 192, r2 = q2 % 192, bg = r2 / 48, kc = r2 % 48;
        int kbase = kc * 16;
        for (int idx = threadIdx.x; idx < 128; idx += 256) {
            int d = idx >> 3, v = idx & 7;
            xs[d][v] = ws[OFF_Q + (i * B + bg * 8 + v) * 768 + kbase + d];
        }
        __syncthreads();
        if (threadIdx.x < 192) {
            GEMV8_K16(Wqc_w + i * D * D + kbase * D + threadIdx.x * 4,
                      OFF_WQC + kc * 73728, (i * 32 + bg * 8))
        }
    }
}

// L2b: coalesced reduce of qk partials (48 slots) -> QK[p][b][d]. 144 blocks x 256.
__global__ __launch_bounds__(256) void k_redqk(float* ws) {
    int idx = blockIdx.x * 256 + threadIdx.x;
    int fidx = idx * 4;
    int row = fidx / 768;
    int j = row / 64, v64 = row % 64;
    int b = v64 & 31, islot = v64 >> 5;
    int i_ = islot ? ((j == 2) ? 1 : 2) : ((j == 0) ? 1 : 0);
    int p = 2 * i_ + ((j < i_) ? j : j - 1);
    int d = fidx % 768;
    float4 a = make_float4(0.f, 0.f, 0.f, 0.f);
    #pragma unroll
    for (int kc = 0; kc < 48; kc++) {
        float4 v = *(const float4*)&ws[OFF_ARENA2 + kc * 147456 + fidx];
        a.x += v.x; a.y += v.y; a.z += v.z; a.w += v.w;
    }
    *(float4*)&ws[OFF_QK + (p * B + b) * D + d] = a;
}

// L3: MEGA-FUSED single feats pass. 256 blocks (b 32, h 8) x 1024 threads.
__global__ __launch_bounds__(1024) void k_fused(const float* feats, const float* eps,
                                                const float* dyn, float* ws) {
    int blk = blockIdx.x;
    int b = blk >> 3, h = blk & 7;
    int t = threadIdx.x;
    int w = t >> 6, lane = t & 63;
    __shared__ __align__(16) float swA[4608];   // WMU[3][768] | WLV[3][768]
    __shared__ __align__(16) float swPK[4608];  // WPK[6][768]
    __shared__ __align__(16) float sqk[4608];   // qk[6][768]
    __shared__ float raws[6][32], pkps[6][32], mus[3][32], lvs[3][32], wgt[6][32];
    __shared__ float klv[96];
    __shared__ float pq_s[6], qbk_s[6], cmu_s[3], clv_s[3], cpk_s[6];
    {
        const float4* srcA = (const float4*)(ws + OFF_WMU);
        const float4* srcP = (const float4*)(ws + OFF_WPK);
        float4* dA = (float4*)swA;
        float4* dP = (float4*)swPK;
        float4* dQ = (float4*)sqk;
        for (int idx = t; idx < 1152; idx += 1024) {
            dA[idx] = srcA[idx];
            dP[idx] = srcP[idx];
            int p = idx / 192, d4 = (idx % 192) * 4;
            dQ[idx] = *(const float4*)&ws[OFF_QK + (p * B + b) * D + d4];
        }
        if (t < 6) { pq_s[t] = ws[OFF_PQ + t * B + b]; qbk_s[t] = ws[OFF_QBK + t * B + b]; cpk_s[t] = ws[OFF_CPK + t]; }
        else if (t < 9) { cmu_s[t - 6] = ws[OFF_CMU + t - 6]; clv_s[t - 6] = ws[OFF_CLV + t - 6]; }
    }
    __syncthreads();
    const float4* swA4 = (const float4*)swA;
    const float4* swPK4 = (const float4*)swPK;
    const float4* sqk4 = (const float4*)sqk;
    for (int tau = w * 6; tau < w * 6 + 6; tau++) {
        int m = tau >> 5, k = tau & 31;
        const float4* row = (const float4*)(feats + ((size_t)((m * B + b) * S) + h * 32 + k) * D);
        float4 x0 = row[lane], x1 = row[lane + 64], x2 = row[lane + 128];
        int i1 = (m == 0) ? 1 : 0, i2 = (m == 2) ? 1 : 2;
        int pj0 = 2 * i1 + ((m < i1) ? m : m - 1);
        int pj1 = 2 * i2 + ((m < i2) ? m : m - 1);
        int oM = m * 192, oL = (3 + m) * 192, o0 = pj0 * 192, o1 = pj1 * 192;
        float dmu = dot4(x0, swA4[oM + lane]) + dot4(x1, swA4[oM + lane + 64]) + dot4(x2, swA4[oM + lane + 128]);
        float dlv = dot4(x0, swA4[oL + lane]) + dot4(x1, swA4[oL + lane + 64]) + dot4(x2, swA4[oL + lane + 128]);
        float dk0 = dot4(x0, swPK4[o0 + lane]) + dot4(x1, swPK4[o0 + lane + 64]) + dot4(x2, swPK4[o0 + lane + 128]);
        float dk1 = dot4(x0, swPK4[o1 + lane]) + dot4(x1, swPK4[o1 + lane + 64]) + dot4(x2, swPK4[o1 + lane + 128]);
        float dr0 = dot4(x0, sqk4[o0 + lane]) + dot4(x1, sqk4[o0 + lane + 64]) + dot4(x2, sqk4[o0 + lane + 128]);
        float dr1 = dot4(x0, sqk4[o1 + lane]) + dot4(x1, sqk4[o1 + lane + 64]) + dot4(x2, sqk4[o1 + lane + 128]);
        dmu = wave_reduce(dmu); dlv = wave_reduce(dlv);
        dk0 = wave_reduce(dk0); dk1 = wave_reduce(dk1);
        dr0 = wave_reduce(dr0); dr1 = wave_reduce(dr1);
        if (lane == 0) {
            mus[m][k] = dmu + cmu_s[m];
            lvs[m][k] = dlv + clv_s[m];
            pkps[pj0][k] = dk0 + cpk_s[pj0];
            pkps[pj1][k] = dk1 + cpk_s[pj1];
            raws[pj0][k] = dr0;
            raws[pj1][k] = dr1;
        }
    }
    __syncthreads();
    float dynv = dyn[0];
    if (t < 192) {
        int p = t >> 5, k = t & 31;
        int iq = p >> 1;
        float e = eps[(size_t)(p * B + b) * S + h * 32 + k];
        float g = sigmoidf(mus[iq][k] + dynv * __expf(0.5f * lvs[iq][k]) * e);
        float pk = sigmoidf(pkps[p][k]) * g;
        float s = (raws[p][k] + qbk_s[p]) * SCALE * pq_s[p] * pk;
        float mc = s;
        #pragma unroll
        for (int o = 16; o > 0; o >>= 1) mc = fmaxf(mc, __shfl_xor(mc, o, 64));
        float wv_ = __expf(s - mc);
        float l = wv_;
        #pragma unroll
        for (int o = 16; o > 0; o >>= 1) l += __shfl_xor(l, o, 64);
        wgt[p][k] = wv_;
        if (k == 0) {
            float* mh = ws + OFF_MLH + (p * B + b) * 16 + h * 2;
            mh[0] = mc; mh[1] = l;
        }
    } else if (t < 288) {
        int tau = t - 192;
        int m = tau >> 5, k = tau & 31;
        float muv = mus[m][k], lvv = lvs[m][k];
        klv[tau] = 1.0f + lvv - muv * muv - __expf(lvv);
    }
    __syncthreads();
    if (t < 768) {
        #pragma unroll
        for (int jm = 0; jm < 3; jm++) {
            int i1 = (jm == 0) ? 1 : 0, i2 = (jm == 2) ? 1 : 2;
            int pj0 = 2 * i1 + ((jm < i1) ? jm : jm - 1);
            int pj1 = 2 * i2 + ((jm < i2) ? jm : jm - 1);
            const float* col = feats + ((size_t)((jm * B + b) * S) + h * 32) * D + t;
            float accA = 0.f, accB = 0.f;
            #pragma unroll 8
            for (int k = 0; k < 32; k++) {
                float fv = col[(size_t)k * D];
                accA += wgt[pj0][k] * fv;
                accB += wgt[pj1][k] * fv;
            }
            ws[OFF_FSUM + h * 147456 + (pj0 * B + b) * D + t] = accA;
            ws[OFF_FSUM + h * 147456 + (pj1 * B + b) * D + t] = accB;
        }
    }
    if (t < 64) {
        float s2 = klv[t] + ((t < 32) ? klv[64 + t] : 0.f);
        s2 = wave_reduce(s2);
        if (t == 0) ws[OFF_KLP + blk] = s2;
    }
}

// L4: agg partials (split-K 48), combining 8 S-chunks via (m,l).
// 1152 blocks (i 3, js 2, bg 4, kc 48) x 192.
__global__ __launch_bounds__(192, 4) void k_agg2(const float* Wv, float* ws) {
    int blk = blockIdx.x;
    int i = blk / 384, r = blk % 384, js = r / 192, r2 = r % 192, bg = r2 / 48, kc = r2 % 48;
    int kbase = kc * 16;
    int j0 = (i == 0) ? 1 : 0, j1 = (i == 2) ? 1 : 2;
    int jv = js ? j1 : j0;
    int p = 2 * i + js;
    __shared__ __align__(16) float xs[16][8];
    __shared__ float comb[8][8];
    if (threadIdx.x < 8) {
        int bb = threadIdx.x;
        const float* mh = ws + OFF_MLH + (p * B + bg * 8 + bb) * 16;
        float mm[8], ll[8];
        float mx = -1e30f;
        #pragma unroll
        for (int hh = 0; hh < 8; hh++) { mm[hh] = mh[2 * hh]; ll[hh] = mh[2 * hh + 1]; mx = fmaxf(mx, mm[hh]); }
        float L = 0.f;
        float ee[8];
        #pragma unroll
        for (int hh = 0; hh < 8; hh++) { ee[hh] = __expf(mm[hh] - mx); L += ee[hh] * ll[hh]; }
        #pragma unroll
        for (int hh = 0; hh < 8; hh++) comb[hh][bb] = ee[hh] / L;
    }
    __syncthreads();
    for (int idx = threadIdx.x; idx < 128; idx += 192) {
        int d = idx >> 3, bb = idx & 7;
        int base = OFF_FSUM + (p * B + bg * 8 + bb) * D + kbase + d;
        float v = 0.f;
        #pragma unroll
        for (int hh = 0; hh < 8; hh++) v += comb[hh][bb] * ws[base + hh * 147456];
        xs[d][bb] = v;
    }
    __syncthreads();
    GEMV8_K16(Wv + jv * D * D + kbase * D + threadIdx.x * 4,
              OFF_ARENA + (js * 48 + kc) * 73728, (i * 32 + bg * 8))
}

// L4b: coalesced reduce agg partials (96 slots) + bv biases -> AGG. 72 blocks x 256.
__global__ __launch_bounds__(256) void k_redA(const float* bv, float* ws) {
    int idx = blockIdx.x * 256 + threadIdx.x;
    int fidx = idx * 4;
    int i = fidx / 24576, e = fidx % 768;
    int j0 = (i == 0) ? 1 : 0, j1 = (i == 2) ? 1 : 2;
    float4 b0 = *(const float4*)&bv[j0 * 768 + e];
    float4 b1 = *(const float4*)&bv[j1 * 768 + e];
    float4 a = make_float4(b0.x + b1.x, b0.y + b1.y, b0.z + b1.z, b0.w + b1.w);
    #pragma unroll
    for (int s = 0; s < 96; s++) {
        float4 p = *(const float4*)&ws[OFF_ARENA + s * 73728 + fidx];
        a.x += p.x; a.y += p.y; a.z += p.z; a.w += p.w;
    }
    *(float4*)&ws[OFF_AGG + fidx] = a;
}

// L5: E/G partials from AGG (split-K 48). 1152 blocks (kind 2, i 3, bg 4, kc 48) x 192.
// kind0: E = AGG@WE (slots 0..47); kind1: G partial = AGG@Wh (slots 48..95).
// (Q@Wqc partials were produced earlier by k_qk into OFF_WQC slots 0..47.)
__global__ __launch_bounds__(192, 4) void k_eg2(const float* WE_w, const float* Wh_w,
                                                float* ws) {
    int blk = blockIdx.x;
    int kind = blk / 576, r = blk % 576;
    int i = r / 192, r2 = r % 192, bg = r2 / 48, kc = r2 % 48;
    int kbase = kc * 16;
    __shared__ __align__(16) float xs[16][8];
    for (int idx = threadIdx.x; idx < 128; idx += 192) {
        int d = idx >> 3, bb = idx & 7;
        xs[d][bb] = ws[OFF_AGG + (i * 32 + bg * 8 + bb) * 768 + kbase + d];
    }
    __syncthreads();
    GEMV8_K16(((kind == 0) ? WE_w : Wh_w) + i * D * D + kbase * D + threadIdx.x * 4,
              OFF_ARENA2 + (kind * 48 + kc) * 73728, (i * 32 + bg * 8))
}

// L5b+L6 merged: reduce E (48 slots) / G (48 Wh + 48 Wqc slots) + bias + relu,
// then LayerNorm(E)*LayerNorm(G) -> FUSED. 96 blocks (i,b) x 256.
__global__ __launch_bounds__(256) void k_redEGLN(const float* WE_b, const float* Wh_b,
        const float* Wqc_b,
        const float* lnE_g, const float* lnE_b,
        const float* lnG_g, const float* lnG_b, float* ws) {
    int blk = blockIdx.x;
    int i = blk / B, b = blk % B;
    int row = (i * B + b) * D;
    int t = threadIdx.x;
    float4 e = make_float4(0.f, 0.f, 0.f, 0.f);
    float4 g = make_float4(0.f, 0.f, 0.f, 0.f);
    if (t < 192) {
        e = *(const float4*)&WE_b[i * D + t * 4];
        float4 b0 = *(const float4*)&Wh_b[i * D + t * 4];
        float4 b1 = *(const float4*)&Wqc_b[i * D + t * 4];
        g = make_float4(b0.x + b1.x, b0.y + b1.y, b0.z + b1.z, b0.w + b1.w);
        #pragma unroll
        for (int s = 0; s < 48; s++) {
            float4 p = *(const float4*)&ws[OFF_ARENA2 + s * 73728 + row + t * 4];
            e.x += p.x; e.y += p.y; e.z += p.z; e.w += p.w;
        }
        #pragma unroll
        for (int s = 48; s < 96; s++) {
            float4 p = *(const float4*)&ws[OFF_ARENA2 + s * 73728 + row + t * 4];
            g.x += p.x; g.y += p.y; g.z += p.z; g.w += p.w;
        }
        #pragma unroll
        for (int s = 0; s < 48; s++) {
            float4 p = *(const float4*)&ws[OFF_WQC + s * 73728 + row + t * 4];
            g.x += p.x; g.y += p.y; g.z += p.z; g.w += p.w;
        }
        e.x = fmaxf(e.x, 0.f); e.y = fmaxf(e.y, 0.f); e.z = fmaxf(e.z, 0.f); e.w = fmaxf(e.w, 0.f);
        g.x = fmaxf(g.x, 0.f); g.y = fmaxf(g.y, 0.f); g.z = fmaxf(g.z, 0.f); g.w = fmaxf(g.w, 0.f);
    }
    __shared__ float r1[256], r2[256], r3[256], r4[256];
    r1[t] = e.x + e.y + e.z + e.w;
    r2[t] = e.x * e.x + e.y * e.y + e.z * e.z + e.w * e.w;
    r3[t] = g.x + g.y + g.z + g.w;
    r4[t] = g.x * g.x + g.y * g.y + g.z * g.z + g.w * g.w;
    __syncthreads();
    for (int st = 128; st > 0; st >>= 1) {
        if (t < st) { r1[t] += r1[t + st]; r2[t] += r2[t + st]; r3[t] += r3[t + st]; r4[t] += r4[t + st]; }
        __syncthreads();
    }
    float mE = r1[0] * (1.0f / D), vE = r2[0] * (1.0f / D) - mE * mE;
    float mG = r3[0] * (1.0f / D), vG = r4[0] * (1.0f / D) - mG * mG;
    float sE = rsqrtf(vE + LN_EPS), sG = rsqrtf(vG + LN_EPS);
    if (t < 192) {
        float4 eg  = *(const float4*)&lnE_g[i * D + t * 4];
        float4 ebv = *(const float4*)&lnE_b[i * D + t * 4];
        float4 gg  = *(const float4*)&lnG_g[i * D + t * 4];
        float4 gbv = *(const float4*)&lnG_b[i * D + t * 4];
        float4 o;
        o.x = ((e.x - mE) * sE * eg.x + ebv.x) * ((g.x - mG) * sG * gg.x + gbv.x);
        o.y = ((e.y - mE) * sE * eg.y + ebv.y) * ((g.y - mG) * sG * gg.y + gbv.y);
        o.z = ((e.z - mE) * sE * eg.z + ebv.z) * ((g.z - mG) * sG * gg.z + gbv.z);
        o.w = ((e.w - mE) * sE * eg.w + ebv.w) * ((g.w - mG) * sG * gg.w + gbv.w);
        *(float4*)&ws[OFF_FUSED + b * MD + i * D + t * 4] = o;
    }
}

// L7: out GEMM partials (bb=8) -> arena. 288 blocks (bg 4, kc 72 (32 k)) x 256.
__global__ __launch_bounds__(256, 4) void k_out2(const float* out_w, float* ws) {
    int blk = blockIdx.x;
    int bg = blk / 72, kc = blk % 72;
    int kbase = kc * 32;
    __shared__ __align__(16) float xs[32][8];
    for (int idx = threadIdx.x; idx < 256; idx += 256) {
        int d = idx & 31, bb = idx >> 5;
        xs[d][bb] = ws[OFF_FUSED + (bg * 8 + bb) * MD + kbase + d];
    }
    __syncthreads();
    int e4 = threadIdx.x * 4;
    const float* Wm = out_w + kbase * H + e4;
    float4 acc[8];
    #pragma unroll
    for (int bb = 0; bb < 8; bb++) acc[bb] = make_float4(0.f, 0.f, 0.f, 0.f);
    for (int k = 0; k < 32; k++) {
        float4 w = *(const float4*)(Wm + k * H);
        float4 x0 = *(const float4*)&xs[k][0];
        float4 x1 = *(const float4*)&xs[k][4];
        fma4(acc[0], x0.x, w); fma4(acc[1], x0.y, w);
        fma4(acc[2], x0.z, w); fma4(acc[3], x0.w, w);
        fma4(acc[4], x1.x, w); fma4(acc[5], x1.y, w);
        fma4(acc[6], x1.z, w); fma4(acc[7], x1.w, w);
    }
    #pragma unroll
    for (int bb = 0; bb < 8; bb++)
        *(float4*)&ws[OFF_ARENA + kc * 32768 + (bg * 8 + bb) * 1024 + e4] = acc[bb];
}

// L7b: sum out partials (72 kc) + bias; block 0 reduces KL partials (256). 32 blocks (b) x 256.
__global__ __launch_bounds__(256) void k_fin(const float* out_b, float* ws, float* out) {
    int b = blockIdx.x;
    int h4 = threadIdx.x * 4;
    float4 a = *(const float4*)&out_b[h4];
    #pragma unroll
    for (int kc = 0; kc < 72; kc++) {
        float4 p = *(const float4*)&ws[OFF_ARENA + kc * 32768 + b * 1024 + h4];
        a.x += p.x; a.y += p.y; a.z += p.z; a.w += p.w;
    }
    *(float4*)&out[b * H + h4] = a;
    if (b == 0) {
        int t = threadIdx.x;
        __shared__ float kls[256];
        kls[t] = ws[OFF_KLP + t];
        __syncthreads();
        for (int st = 128; st > 0; st >>= 1) {
            if (t < st) kls[t] += kls[t + st];
            __syncthreads();
        }
        if (t == 0) out[B * H] = -kls[0];
    }
}

extern "C" void kernel_launch(void* const* d_in, const int* in_sizes, int n_in,
                              void* d_out, int out_size, void* d_ws, size_t ws_size,
                              hipStream_t stream) {
    const float* feats = (const float*)d_in[0];
    const float* Wq    = (const float*)d_in[1];
    const float* bq    = (const float*)d_in[2];
    const float* Wk    = (const float*)d_in[3];
    const float* bk    = (const float*)d_in[4];
    const float* Wv    = (const float*)d_in[5];
    const float* bv    = (const float*)d_in[6];
    const float* pgq_w = (const float*)d_in[7];
    const float* pgq_b = (const float*)d_in[8];
    const float* pgk_w = (const float*)d_in[9];
    const float* pgk_b = (const float*)d_in[10];
    const float* mu_w  = (const float*)d_in[11];
    const float* mu_b  = (const float*)d_in[12];
    const float* lv_w  = (const float*)d_in[13];
    const float* lv_b  = (const float*)d_in[14];
    const float* dyn   = (const float*)d_in[15];
    const float* WE_w  = (const float*)d_in[16];
    const float* WE_b  = (const float*)d_in[17];
    const float* Wh_w  = (const float*)d_in[18];
    const float* Wh_b  = (const float*)d_in[19];
    const float* Wqc_w = (const float*)d_in[20];
    const float* Wqc_b = (const float*)d_in[21];
    const float* lnE_g = (const float*)d_in[22];
    const float* lnE_b = (const float*)d_in[23];
    const float* lnG_g = (const float*)d_in[24];
    const float* lnG_b = (const float*)d_in[25];
    const float* out_w = (const float*)d_in[26];
    const float* out_b = (const float*)d_in[27];
    const float* eps   = (const float*)d_in[28];
    float* ws  = (float*)d_ws;
    float* out = (float*)d_out;

    k_prep2<<<1095, 256, 0, stream>>>(feats, Wq, Wk, bq, bk, mu_w, mu_b, lv_w, lv_b,
                                      pgq_w, pgq_b, pgk_w, pgk_b, ws);
    k_redQ<<<96, 256, 0, stream>>>(feats, bq, bk, eps, dyn, ws);
    k_qk<<<1728, 256, 0, stream>>>(Wqc_w, ws);
    k_redqk<<<144, 256, 0, stream>>>(ws);
    k_fused<<<256, 1024, 0, stream>>>(feats, eps, dyn, ws);
    k_agg2<<<1152, 192, 0, stream>>>(Wv, ws);
    k_redA<<<72, 256, 0, stream>>>(bv, ws);
    k_eg2<<<1152, 192, 0, stream>>>(WE_w, Wh_w, ws);
    k_redEGLN<<<96, 256, 0, stream>>>(WE_b, Wh_b, Wqc_b, lnE_g, lnE_b, lnG_g, lnG_b, ws);
    k_out2<<<288, 256, 0, stream>>>(out_w, ws);
    k_fin<<<32, 256, 0, stream>>>(out_b, ws, out);
}